// Round 1
// baseline (170.158 us; speedup 1.0000x reference)
//
#include <hip/hip_runtime.h>
#include <hip/hip_bf16.h>

typedef __attribute__((ext_vector_type(4))) float f32x4;
typedef __attribute__((ext_vector_type(8))) short bf16x8;

#define T_LEN 2048
#define ENC   512
#define DEC   1024
#define ATT   128
#define NB    64
#define KP    544   // 512 keys + 31 conv taps + 1 zero pad
#define BM    128
#define BK    32

__device__ __forceinline__ unsigned short f2bf(float x) {
  unsigned int u = __builtin_bit_cast(unsigned int, x);
  u += 0x7fff + ((u >> 16) & 1);   // RNE
  return (unsigned short)(u >> 16);
}

__device__ __forceinline__ float fast_tanh(float x) {
  float e = __expf(2.f * x);
  return 1.f - 2.f / (e + 1.f);    // robust at +-inf
}

// ---------------- prep 1: pq = query@W2  (b<64), CW = conv_w^T @ loc_dense (b==64)
__global__ __launch_bounds__(128) void prep1(
    const float* __restrict__ query, const float* __restrict__ W2,
    const float* __restrict__ convw, const float* __restrict__ ldense,
    float* __restrict__ pq, float* __restrict__ CW) {
  int a = threadIdx.x;
  int b = blockIdx.x;
  if (b < NB) {
    float acc = 0.f;
    for (int d = 0; d < DEC; ++d) acc += query[b * DEC + d] * W2[d * ATT + a];
    pq[b * ATT + a] = acc;
  } else {
    for (int k = 0; k < 31; ++k) {
      float acc = 0.f;
      #pragma unroll
      for (int f = 0; f < 32; ++f) acc += convw[f * 31 + k] * ldense[f * ATT + a];
      CW[k * ATT + a] = acc;
    }
  }
}

// ---------------- prep 2: BmatT[a][k] = bf16( k<512 ? W1[k][a] : k<543 ? CW[k-512][a] : 0 )
__global__ __launch_bounds__(256) void prep2(
    const float* __restrict__ W1, const float* __restrict__ CW,
    unsigned short* __restrict__ BmatT) {
  int a = blockIdx.x;
  for (int k = threadIdx.x; k < KP; k += 256) {
    float v = 0.f;
    if (k < 512) v = W1[k * ATT + a];
    else if (k < 543) v = CW[(k - 512) * ATT + a];
    BmatT[a * KP + k] = f2bf(v);
  }
}

// ---------------- main: fused GEMM(keys|prev vs W1|CW) + tanh·V + mask + exp + partial ctx
__global__ __launch_bounds__(256) void lsa_main(
    const float* __restrict__ keys, const float* __restrict__ prev,
    const int* __restrict__ mask, const unsigned short* __restrict__ BmatT,
    const float* __restrict__ pq, const float* __restrict__ Vv,
    float* __restrict__ wout, float* __restrict__ dpart, float* __restrict__ cpart) {
  __shared__ unsigned short Ash[BM * BK];
  __shared__ unsigned short Bsh[ATT * BK];
  __shared__ float s_red[2][BM];
  __shared__ float e_vals[BM];

  const int tid = threadIdx.x;
  const int b = blockIdx.y;
  const int trow0 = blockIdx.x * BM;
  const int bid = b * gridDim.x + blockIdx.x;

  const int lane = tid & 63;
  const int w = tid >> 6;
  const int wr = w >> 1, wc = w & 1;
  const int rsel = lane & 15, grp = lane >> 4;

  f32x4 acc[4][4];
  #pragma unroll
  for (int m = 0; m < 4; ++m)
    #pragma unroll
    for (int n = 0; n < 4; ++n) acc[m][n] = (f32x4)0.f;

  const int srow = tid >> 1;   // 0..127 (A row / B col)
  const int shalf = tid & 1;   // which 16-element k half
  const int sswz = (srow & 3) ^ ((srow >> 2) & 3);

  for (int kt = 0; kt < 17; ++kt) {
    const int kbase = kt * BK;
    __syncthreads();
    // ---- stage A: keys (fp32->bf16) or prev window (last step) ----
    float vals[16];
    if (kt < 16) {
      const f32x4* g = reinterpret_cast<const f32x4*>(
          keys + ((size_t)b * T_LEN + trow0 + srow) * ENC + kbase + shalf * 16);
      *reinterpret_cast<f32x4*>(&vals[0])  = g[0];
      *reinterpret_cast<f32x4*>(&vals[4])  = g[1];
      *reinterpret_cast<f32x4*>(&vals[8])  = g[2];
      *reinterpret_cast<f32x4*>(&vals[12]) = g[3];
    } else {
      #pragma unroll
      for (int j = 0; j < 16; ++j) {
        int kk = shalf * 16 + j;
        int pos = trow0 + srow + kk - 15;
        float v = 0.f;
        if (kk < 31 && pos >= 0 && pos < T_LEN) v = prev[b * T_LEN + pos];
        vals[j] = v;
      }
    }
    #pragma unroll
    for (int s2 = 0; s2 < 2; ++s2) {
      int slot = shalf * 2 + s2;
      bf16x8 pk;
      #pragma unroll
      for (int j = 0; j < 8; ++j) pk[j] = (short)f2bf(vals[s2 * 8 + j]);
      *reinterpret_cast<bf16x8*>(&Ash[srow * BK + ((slot ^ sswz) * 8)]) = pk;
    }
    // ---- stage B (already bf16, transposed: [col][k]) ----
    {
      const bf16x8* gb = reinterpret_cast<const bf16x8*>(BmatT + srow * KP + kbase + shalf * 16);
      #pragma unroll
      for (int s2 = 0; s2 < 2; ++s2) {
        int slot = shalf * 2 + s2;
        bf16x8 pv = gb[s2];
        *reinterpret_cast<bf16x8*>(&Bsh[srow * BK + ((slot ^ sswz) * 8)]) = pv;
      }
    }
    __syncthreads();
    // ---- fragment loads + 16 MFMA ----
    bf16x8 af[4], bfr[4];
    #pragma unroll
    for (int m = 0; m < 4; ++m) {
      int r = wr * 64 + m * 16 + rsel;
      int swz = (r & 3) ^ ((r >> 2) & 3);
      af[m] = *reinterpret_cast<const bf16x8*>(&Ash[r * BK + ((grp ^ swz) * 8)]);
    }
    #pragma unroll
    for (int n = 0; n < 4; ++n) {
      int c = wc * 64 + n * 16 + rsel;
      int swz = (c & 3) ^ ((c >> 2) & 3);
      bfr[n] = *reinterpret_cast<const bf16x8*>(&Bsh[c * BK + ((grp ^ swz) * 8)]);
    }
    #pragma unroll
    for (int m = 0; m < 4; ++m)
      #pragma unroll
      for (int n = 0; n < 4; ++n)
        acc[m][n] = __builtin_amdgcn_mfma_f32_16x16x32_bf16(af[m], bfr[n], acc[m][n], 0, 0, 0);
  }

  // ---- epilogue: scores = sum_a V[a]*tanh(acc + pq) ----
  float psum[4][4];
  #pragma unroll
  for (int m = 0; m < 4; ++m)
    #pragma unroll
    for (int i = 0; i < 4; ++i) psum[m][i] = 0.f;
  #pragma unroll
  for (int n = 0; n < 4; ++n) {
    int c = wc * 64 + n * 16 + rsel;
    float pqv = pq[b * ATT + c];
    float vv = Vv[c];
    #pragma unroll
    for (int m = 0; m < 4; ++m)
      #pragma unroll
      for (int i = 0; i < 4; ++i)
        psum[m][i] += vv * fast_tanh(acc[m][n][i] + pqv);
  }
  #pragma unroll
  for (int m = 0; m < 4; ++m)
    #pragma unroll
    for (int i = 0; i < 4; ++i) {
      float v = psum[m][i];
      v += __shfl_xor(v, 1, 64);
      v += __shfl_xor(v, 2, 64);
      v += __shfl_xor(v, 4, 64);
      v += __shfl_xor(v, 8, 64);
      psum[m][i] = v;
    }
  if (rsel == 0) {
    #pragma unroll
    for (int m = 0; m < 4; ++m)
      #pragma unroll
      for (int i = 0; i < 4; ++i)
        s_red[wc][wr * 64 + m * 16 + grp * 4 + i] = psum[m][i];
  }
  __syncthreads();

  if (tid < BM) {
    int trow = trow0 + tid;
    float s = s_red[0][tid] + s_red[1][tid];
    float e = (mask[b * T_LEN + trow] == 0) ? 0.f : __expf(s);
    wout[b * T_LEN + trow] = e;       // unnormalized; finalize scales
    e_vals[tid] = e;
  }
  __syncthreads();

  if (tid < 64) {
    float v = e_vals[tid] + e_vals[tid + 64];
    #pragma unroll
    for (int off = 32; off; off >>= 1) v += __shfl_xor(v, off, 64);
    if (tid == 0) dpart[bid] = v;
  }

  // ---- partial context: sum_t e_t * keys[t,:], keys tile is L2-hot ----
  float c0 = 0.f, c1 = 0.f;
  const float* krow = keys + ((size_t)b * T_LEN + trow0) * ENC;
  for (int r = 0; r < BM; ++r) {
    float e = e_vals[r];
    if (e != 0.f) {
      c0 += e * krow[(size_t)r * ENC + tid];
      c1 += e * krow[(size_t)r * ENC + tid + 256];
    }
  }
  cpart[(size_t)bid * ENC + tid] = c0;
  cpart[(size_t)bid * ENC + tid + 256] = c1;
}

// ---------------- finalize: normalize weights + reduce context partials
__global__ __launch_bounds__(256) void lsa_finalize(
    const float* __restrict__ dpart, const float* __restrict__ cpart,
    float* __restrict__ out) {
  int b = blockIdx.x, tid = threadIdx.x;
  float d = 0.f;
  #pragma unroll
  for (int i = 0; i < 16; ++i) d += dpart[b * 16 + i];
  float inv = 1.f / d;
  for (int e = tid; e < ENC; e += 256) {
    float c = 0.f;
    #pragma unroll
    for (int i = 0; i < 16; ++i) c += cpart[((size_t)(b * 16 + i)) * ENC + e];
    out[b * ENC + e] = c * inv;
  }
  float* wrow = out + NB * ENC + (size_t)b * T_LEN;
  for (int t = tid; t < T_LEN; t += 256) wrow[t] *= inv;
}

extern "C" void kernel_launch(void* const* d_in, const int* in_sizes, int n_in,
                              void* d_out, int out_size, void* d_ws, size_t ws_size,
                              hipStream_t stream) {
  const float* query  = (const float*)d_in[0];
  const float* keys   = (const float*)d_in[1];
  const float* prev   = (const float*)d_in[2];
  const int*   mask   = (const int*)d_in[3];
  const float* W1     = (const float*)d_in[4];
  const float* W2     = (const float*)d_in[5];
  const float* V      = (const float*)d_in[6];
  const float* convw  = (const float*)d_in[7];
  const float* ldense = (const float*)d_in[8];
  float* out = (float*)d_out;

  char* ws = (char*)d_ws;
  unsigned short* BmatT = (unsigned short*)ws;                    // 139264 B
  float* pq    = (float*)(ws + 139264);                           // 32768 B
  float* CW    = (float*)(ws + 139264 + 32768);                   // 15872 B
  float* dpart = (float*)(ws + 139264 + 32768 + 15872);           // 4096 B
  float* cpart = (float*)(ws + 139264 + 32768 + 15872 + 4096);    // 2 MB

  prep1<<<dim3(65), dim3(128), 0, stream>>>(query, W2, convw, ldense, pq, CW);
  prep2<<<dim3(128), dim3(256), 0, stream>>>(W1, CW, BmatT);
  dim3 grid(16, 64);
  lsa_main<<<grid, dim3(256), 0, stream>>>(keys, prev, mask, BmatT, pq, V,
                                           out + NB * ENC, dpart, cpart);
  lsa_finalize<<<dim3(NB), dim3(256), 0, stream>>>(dpart, cpart, out);
}